// Round 6
// baseline (107.723 us; speedup 1.0000x reference)
//
#include <hip/hip_runtime.h>
#include <hip/hip_fp16.h>

#define DEVI __device__ __forceinline__

typedef float f32x4 __attribute__((ext_vector_type(4)));
typedef float float4v __attribute__((ext_vector_type(4)));
typedef _Float16 f16x8 __attribute__((ext_vector_type(8)));
typedef unsigned short us8 __attribute__((ext_vector_type(8)));

constexpr int NB = 32, TC = 2048, TQ = 256, DD = 256;
constexpr int CR = 64;                      // c-rows per kA block
constexpr float VNEG = -1e29f;

DEVI unsigned short f2h(float f) {
  _Float16 h = (_Float16)f;                 // v_cvt_f16_f32 (RN)
  return __builtin_bit_cast(unsigned short, h);
}
DEVI float h2f(unsigned short u) {
  return (float)__builtin_bit_cast(_Float16, u);
}

// XOR swizzle on 16B granules within a 512B row; involution (write==read).
DEVI int swz(int row, int cb) { return cb ^ (((row ^ (cb >> 7)) & 7) << 4); }

DEVI f32x4 mfmah(us8 a, us8 b, f32x4 c) {
  return __builtin_amdgcn_mfma_f32_16x16x32_f16(
      __builtin_bit_cast(f16x8, a), __builtin_bit_cast(f16x8, b), c, 0, 0, 0);
}

// ---------------------------------------------------------------------------
// P0: one pass over Q producing Qh (fp16 row-major) AND QT (fp16 transposed).
// 512 blocks: one 64x64 tile each.
// ---------------------------------------------------------------------------
__global__ void P0(const float* __restrict__ Qg, unsigned short* __restrict__ Qh,
                   unsigned short* __restrict__ QT)
{
  __shared__ unsigned short t[64][72];
  const int bid = blockIdx.x, tid = threadIdx.x;
  const int b = bid >> 4;
  const int q0 = ((bid >> 2) & 3) * 64, d0 = (bid & 3) * 64;
  {
    const int qr = tid >> 2, dp = (tid & 3) * 16;
    const float* src = Qg + ((size_t)b * TQ + q0 + qr) * DD + d0 + dp;
    unsigned short* dst = Qh + ((size_t)b * TQ + q0 + qr) * DD + d0 + dp;
    us8 o0, o1;
#pragma unroll
    for (int i = 0; i < 4; ++i) {
      float4v v = *(const float4v*)(src + i * 4);
#pragma unroll
      for (int j = 0; j < 4; ++j) {
        const unsigned short h = f2h(v[j]);
        t[qr][dp + i * 4 + j] = h;
        if (i < 2) o0[i * 4 + j] = h; else o1[(i - 2) * 4 + j] = h;
      }
    }
    *(us8*)dst = o0;
    *(us8*)(dst + 8) = o1;
  }
  __syncthreads();
  {
    const int dr = tid >> 2, qp = (tid & 3) * 16;
    us8 a, c;
#pragma unroll
    for (int i = 0; i < 8; ++i) a[i] = t[qp + i][dr];
#pragma unroll
    for (int i = 0; i < 8; ++i) c[i] = t[qp + 8 + i][dr];
    unsigned short* dst = QT + ((size_t)b * DD + d0 + dr) * TQ + q0 + qp;
    *(us8*)dst = a;
    *(us8*)(dst + 8) = c;
  }
}

// ---------------------------------------------------------------------------
// Kernel A: per (batch, 64-row c-tile), 512 threads = 8 waves; wave tile
// 64c x 32q (sim) / 64c x 32d (PV) -> acc[4][2] = 32 AGPRs, arch VGPRs fit
// in 128 total (4 waves/SIMD, no spills). fp16 MFMA. C staged once in LDS;
// Q operands from global (L2-resident) with register prefetch.
// Emits q2c per-tile partials (pnum split in 2 row-halves, ptM, ptD).
// ---------------------------------------------------------------------------
__global__ __launch_bounds__(512, 2)
void kA(const float* __restrict__ Cg, const unsigned short* __restrict__ Qh,
        const unsigned short* __restrict__ QT,
        const int* __restrict__ clenp, const int* __restrict__ qlenp,
        float* __restrict__ out1, float* __restrict__ pnum,
        float* __restrict__ ptM, float* __restrict__ ptD)
{
  __shared__ __align__(16) char lds[32768];  // bufC (fp16), later bufP
  __shared__ float red[512];                 // [8 waves][64 rows]
  __shared__ float wred[64];                 // row max M_c
  __shared__ float wexp[64];                 // exp(M_c - mtile)
  char* const bufC = lds;
  char* const bufP = lds;

  const int bid = blockIdx.x;
  const int b = bid & 31;                   // batch -> fixed XCD (bid%8 == b%8)
  const int tile = bid >> 5;                // 0..31
  const int c0 = tile * CR;
  const int tid = threadIdx.x;
  const int l = tid & 63, wid = tid >> 6;   // 8 waves
  const int g = l >> 4, lm = l & 15;
  const int clen = clenp[b], qlen = qlenp[b];

  const float* Cb = Cg + (size_t)(b * TC + c0) * DD;
  const unsigned short* Qhb = Qh + (size_t)b * TQ * DD;
  const unsigned short* QTb = QT + (size_t)b * DD * TQ;

  // ---- stage C tile once: 64 rows x 256 d fp32 -> fp16 LDS ----
  {
    const int r = tid >> 3;                 // 64 rows, 8 threads/row
    const int d0 = (tid & 7) * 32;
    const float* src = Cb + (size_t)r * DD + d0;
#pragma unroll
    for (int i = 0; i < 4; ++i) {
      us8 h;
#pragma unroll
      for (int k = 0; k < 8; k += 4) {
        float4v v = *(const float4v*)(src + i * 8 + k);
#pragma unroll
        for (int j = 0; j < 4; ++j) h[k + j] = f2h(v[j]);
      }
      *(us8*)(bufC + r * 512 + swz(r, (d0 + i * 8) * 2)) = h;
    }
  }
  __syncthreads();   // bar1

  f32x4 acc[4][2];
#pragma unroll
  for (int mt = 0; mt < 4; ++mt)
#pragma unroll
    for (int nt = 0; nt < 2; ++nt) acc[mt][nt] = (f32x4)0.0f;

  // ---- sim: A (C rows) from LDS, B (Q rows) from global, prefetched ----
  us8 bh[2][2];
#pragma unroll
  for (int nt = 0; nt < 2; ++nt)
    bh[0][nt] = *(const us8*)(Qhb + (size_t)(wid * 32 + nt * 16 + lm) * DD + g * 8);
#pragma unroll
  for (int kk = 0; kk < 8; ++kk) {
    const int cur = kk & 1, nxt = cur ^ 1;
    if (kk < 7) {
#pragma unroll
      for (int nt = 0; nt < 2; ++nt)
        bh[nxt][nt] = *(const us8*)(Qhb + (size_t)(wid * 32 + nt * 16 + lm) * DD +
                                    (kk + 1) * 32 + g * 8);
    }
    us8 ah[4];
#pragma unroll
    for (int mt = 0; mt < 4; ++mt) {
      const int row = mt * 16 + lm;
      ah[mt] = *(const us8*)(bufC + row * 512 + swz(row, kk * 64 + g * 16));
    }
#pragma unroll
    for (int mt = 0; mt < 4; ++mt)
#pragma unroll
      for (int nt = 0; nt < 2; ++nt)
        acc[mt][nt] = mfmah(ah[mt], bh[cur][nt], acc[mt][nt]);
  }

  // ---- mask (exact fp32 absorption to -1e29, as reference) ----
#pragma unroll
  for (int nt = 0; nt < 2; ++nt) {
    const int q = wid * 32 + nt * 16 + lm;
    const bool qm = q >= qlen;
#pragma unroll
    for (int mt = 0; mt < 4; ++mt)
#pragma unroll
      for (int j = 0; j < 4; ++j) {
        const int c = c0 + mt * 16 + g * 4 + j;
        if (qm || c >= clen) acc[mt][nt][j] = VNEG;
      }
  }

  // ---- softmax over q (wave-local shuffle + cross-wave LDS, 8 waves) ----
  float rmax[4][4], rsum[4][4];
#pragma unroll
  for (int mt = 0; mt < 4; ++mt)
#pragma unroll
    for (int j = 0; j < 4; ++j) {
      float m = fmaxf(acc[mt][0][j], acc[mt][1][j]);
      m = fmaxf(m, __shfl_xor(m, 1, 64));
      m = fmaxf(m, __shfl_xor(m, 2, 64));
      m = fmaxf(m, __shfl_xor(m, 4, 64));
      m = fmaxf(m, __shfl_xor(m, 8, 64));
      rmax[mt][j] = m;
    }
  if (lm == 0) {
#pragma unroll
    for (int mt = 0; mt < 4; ++mt)
#pragma unroll
      for (int j = 0; j < 4; ++j)
        red[wid * 64 + mt * 16 + g * 4 + j] = rmax[mt][j];
  }
  __syncthreads();   // bar2
#pragma unroll
  for (int mt = 0; mt < 4; ++mt)
#pragma unroll
    for (int j = 0; j < 4; ++j) {
      const int row = mt * 16 + g * 4 + j;
      const float m0 = fmaxf(fmaxf(red[row], red[64 + row]),
                             fmaxf(red[128 + row], red[192 + row]));
      const float m1 = fmaxf(fmaxf(red[256 + row], red[320 + row]),
                             fmaxf(red[384 + row], red[448 + row]));
      rmax[mt][j] = fmaxf(m0, m1);
      if (wid == 0 && lm == 0) wred[row] = rmax[mt][j];
    }
  // tile max (over all 64 rows): local 16 rows then across g
  float mtile;
  {
    float m = rmax[0][0];
#pragma unroll
    for (int mt = 0; mt < 4; ++mt)
#pragma unroll
      for (int j = 0; j < 4; ++j) m = fmaxf(m, rmax[mt][j]);
    m = fmaxf(m, __shfl_xor(m, 16, 64));
    m = fmaxf(m, __shfl_xor(m, 32, 64));
    mtile = m;
  }
  // exp + wave partial sums
#pragma unroll
  for (int mt = 0; mt < 4; ++mt)
#pragma unroll
    for (int j = 0; j < 4; ++j) {
      float s = 0.f;
#pragma unroll
      for (int nt = 0; nt < 2; ++nt) {
        const float p = __expf(acc[mt][nt][j] - rmax[mt][j]);
        acc[mt][nt][j] = p;
        s += p;
      }
      s += __shfl_xor(s, 1, 64);
      s += __shfl_xor(s, 2, 64);
      s += __shfl_xor(s, 4, 64);
      s += __shfl_xor(s, 8, 64);
      rsum[mt][j] = s;
    }
  __syncthreads();   // bar3 (red-max reads done; wred visible)
  if (lm == 0) {
#pragma unroll
    for (int mt = 0; mt < 4; ++mt)
#pragma unroll
      for (int j = 0; j < 4; ++j)
        red[wid * 64 + mt * 16 + g * 4 + j] = rsum[mt][j];
  }
  if (wid == 0) {
    const float wv = __expf(wred[l] - mtile);
    wexp[l] = wv;
    float s = wv;
    s += __shfl_xor(s, 1, 64);  s += __shfl_xor(s, 2, 64);
    s += __shfl_xor(s, 4, 64);  s += __shfl_xor(s, 8, 64);
    s += __shfl_xor(s, 16, 64); s += __shfl_xor(s, 32, 64);
    if (l == 0) { ptD[b * 32 + tile] = s; ptM[b * 32 + tile] = mtile; }
  }
  __syncthreads();   // bar4 (red-sum + wexp visible)
#pragma unroll
  for (int mt = 0; mt < 4; ++mt)
#pragma unroll
    for (int j = 0; j < 4; ++j) {
      const int row = mt * 16 + g * 4 + j;
      const float s0 = (red[row] + red[64 + row]) + (red[128 + row] + red[192 + row]);
      const float s1 = (red[256 + row] + red[320 + row]) + (red[384 + row] + red[448 + row]);
      rsum[mt][j] = s0 + s1;
    }

  // ---- q2c partial from LDS C-tile: pnum[half][d] = sum_{r in half} wexp[r]*C[r,d]
  {
    const int half = tid >> 8;              // 0/1 -> rows 0..31 / 32..63
    const int d = tid & 255;
    float qacc = 0.f;
    const int d2 = d * 2;
#pragma unroll 8
    for (int r = half * 32; r < half * 32 + 32; ++r) {
      const float cv = h2f(*(const unsigned short*)(bufC + r * 512 + swz(r, d2)));
      qacc += wexp[r] * cv;
    }
    pnum[(((size_t)b * 32 + tile) * 2 + half) * DD + d] = qacc;
  }
  __syncthreads();   // bar5 (bufC reads done; safe to overwrite with P)

  // ---- write P (un-normalized exp, fp16) into bufP (aliases bufC) ----
#pragma unroll
  for (int mt = 0; mt < 4; ++mt)
#pragma unroll
    for (int nt = 0; nt < 2; ++nt)
#pragma unroll
      for (int j = 0; j < 4; ++j) {
        const int row = mt * 16 + g * 4 + j;
        const int cb = (wid * 32 + nt * 16 + lm) * 2;
        *(unsigned short*)(bufP + row * 512 + swz(row, cb)) = f2h(acc[mt][nt][j]);
      }
  __syncthreads();   // bar6 (P visible)

  // ---- PV: out1 = P @ Q; A from LDS P, B from global QT, prefetched ----
  f32x4 pacc[4][2];
#pragma unroll
  for (int mt = 0; mt < 4; ++mt)
#pragma unroll
    for (int dt = 0; dt < 2; ++dt) pacc[mt][dt] = (f32x4)0.0f;

  us8 qb[2][2];
#pragma unroll
  for (int dt = 0; dt < 2; ++dt)
    qb[0][dt] = *(const us8*)(QTb + (size_t)(wid * 32 + dt * 16 + lm) * TQ + g * 8);
#pragma unroll
  for (int kq = 0; kq < 8; ++kq) {
    const int cur = kq & 1, nxt = cur ^ 1;
    if (kq < 7) {
#pragma unroll
      for (int dt = 0; dt < 2; ++dt)
        qb[nxt][dt] = *(const us8*)(QTb + (size_t)(wid * 32 + dt * 16 + lm) * TQ +
                                    (kq + 1) * 32 + g * 8);
    }
    us8 pa[4];
#pragma unroll
    for (int mt = 0; mt < 4; ++mt) {
      const int row = mt * 16 + lm;
      pa[mt] = *(const us8*)(bufP + row * 512 + swz(row, kq * 64 + g * 16));
    }
#pragma unroll
    for (int mt = 0; mt < 4; ++mt)
#pragma unroll
      for (int dt = 0; dt < 2; ++dt)
        pacc[mt][dt] = mfmah(pa[mt], qb[cur][dt], pacc[mt][dt]);
  }

  // ---- epilogue: normalize and store ----
#pragma unroll
  for (int mt = 0; mt < 4; ++mt)
#pragma unroll
    for (int j = 0; j < 4; ++j) {
      const float inv = 1.0f / rsum[mt][j];
      const size_t rowoff = (size_t)(b * TC + c0 + mt * 16 + g * 4 + j) * DD;
#pragma unroll
      for (int dt = 0; dt < 2; ++dt)
        out1[rowoff + wid * 32 + dt * 16 + lm] = pacc[mt][dt][j] * inv;
    }
}

// ---------------------------------------------------------------------------
// kComb: q2c[b,d] = sum_t e^{ptM_t - m} (pnum[t,0,d]+pnum[t,1,d]) /
//                   (sum_t e^{ptM_t - m} ptD_t)
// ---------------------------------------------------------------------------
__global__ void kComb(const float* __restrict__ pnum, const float* __restrict__ ptM,
                      const float* __restrict__ ptD, float* __restrict__ q2c)
{
  const int b = blockIdx.x, tid = threadIdx.x;
  __shared__ float sM[32], sD[32];
  if (tid < 32) { sM[tid] = ptM[b * 32 + tid]; sD[tid] = ptD[b * 32 + tid]; }
  __syncthreads();
  float m = sM[0];
#pragma unroll
  for (int t = 1; t < 32; ++t) m = fmaxf(m, sM[t]);
  float den = 0.f, acc = 0.f;
#pragma unroll
  for (int t = 0; t < 32; ++t) {
    const float sc = __expf(sM[t] - m);
    den += sc * sD[t];
    const size_t base = (((size_t)b * 32 + t) * 2) * DD + tid;
    acc += sc * (pnum[base] + pnum[base + DD]);
  }
  q2c[b * DD + tid] = acc / den;
}

// ---------------------------------------------------------------------------
// kC: broadcast q2c[b,d] -> out2[b, c-seg, d]
// ---------------------------------------------------------------------------
__global__ void kC(const float* __restrict__ q2c, float* __restrict__ out2)
{
  const int b = blockIdx.x >> 4, seg = blockIdx.x & 15;
  const int d = threadIdx.x;
  const float s = q2c[b * DD + d];
  float* dst = out2 + ((size_t)b * TC + seg * 128) * DD + d;
#pragma unroll 4
  for (int c = 0; c < 128; ++c) dst[(size_t)c * DD] = s;
}

extern "C" void kernel_launch(void* const* d_in, const int* in_sizes, int n_in,
                              void* d_out, int out_size, void* d_ws, size_t ws_size,
                              hipStream_t stream)
{
  const float* Cg = (const float*)d_in[0];
  const float* Qg = (const float*)d_in[1];
  const int* clen = (const int*)d_in[2];
  const int* qlen = (const int*)d_in[3];
  float* out1 = (float*)d_out;
  float* out2 = out1 + (size_t)NB * TC * DD;

  char* ws = (char*)d_ws;
  float* pnum = (float*)(ws);                          // 32*32*2*256 f32 = 2 MB
  float* ptM  = (float*)(ws + 2097152);                // 1024 f32
  float* ptD  = (float*)(ws + 2101248);                // 1024 f32
  float* q2c  = (float*)(ws + 2105344);                // 32*256 f32
  unsigned short* Qh = (unsigned short*)(ws + 2138112);          // 4 MB
  unsigned short* QT = (unsigned short*)(ws + 2138112 + 4194304);// 4 MB

  P0   <<<dim3(512), dim3(256), 0, stream>>>(Qg, Qh, QT);
  kA   <<<dim3(NB * (TC / CR)), dim3(512), 0, stream>>>(Cg, Qh, QT, clen, qlen,
                                                        out1, pnum, ptM, ptD);
  kComb<<<dim3(NB), dim3(256), 0, stream>>>(pnum, ptM, ptD, q2c);
  kC   <<<dim3(NB * 16), dim3(256), 0, stream>>>(q2c, out2);
}

// Round 7
// 86.176 us; speedup vs baseline: 1.2500x; 1.2500x over previous
//
#include <hip/hip_runtime.h>
#include <hip/hip_fp16.h>

#define DEVI __device__ __forceinline__

typedef float f32x4 __attribute__((ext_vector_type(4)));
typedef float float4v __attribute__((ext_vector_type(4)));
typedef _Float16 f16x8 __attribute__((ext_vector_type(8)));
typedef unsigned short us8 __attribute__((ext_vector_type(8)));

constexpr int NB = 32, TC = 2048, TQ = 256, DD = 256;
constexpr int CR = 64;                      // c-rows per kA block
constexpr float VNEG = -1e29f;

DEVI unsigned short f2h(float f) {
  _Float16 h = (_Float16)f;                 // v_cvt_f16_f32 (RN)
  return __builtin_bit_cast(unsigned short, h);
}
DEVI float h2f(unsigned short u) {
  return (float)__builtin_bit_cast(_Float16, u);
}

// XOR swizzle on 16B granules within a 512B row; involution (write==read).
DEVI int swz(int row, int cb) { return cb ^ (((row ^ (cb >> 7)) & 7) << 4); }

DEVI f32x4 mfmah(us8 a, us8 b, f32x4 c) {
  return __builtin_amdgcn_mfma_f32_16x16x32_f16(
      __builtin_bit_cast(f16x8, a), __builtin_bit_cast(f16x8, b), c, 0, 0, 0);
}

// ---------------------------------------------------------------------------
// P0: one pass over Q producing Qh (fp16 row-major) AND QT (fp16 transposed).
// 512 blocks: one 64x64 tile each.
// ---------------------------------------------------------------------------
__global__ void P0(const float* __restrict__ Qg, unsigned short* __restrict__ Qh,
                   unsigned short* __restrict__ QT)
{
  __shared__ unsigned short t[64][72];
  const int bid = blockIdx.x, tid = threadIdx.x;
  const int b = bid >> 4;
  const int q0 = ((bid >> 2) & 3) * 64, d0 = (bid & 3) * 64;
  {
    const int qr = tid >> 2, dp = (tid & 3) * 16;
    const float* src = Qg + ((size_t)b * TQ + q0 + qr) * DD + d0 + dp;
    unsigned short* dst = Qh + ((size_t)b * TQ + q0 + qr) * DD + d0 + dp;
    us8 o0, o1;
#pragma unroll
    for (int i = 0; i < 4; ++i) {
      float4v v = *(const float4v*)(src + i * 4);
#pragma unroll
      for (int j = 0; j < 4; ++j) {
        const unsigned short h = f2h(v[j]);
        t[qr][dp + i * 4 + j] = h;
        if (i < 2) o0[i * 4 + j] = h; else o1[(i - 2) * 4 + j] = h;
      }
    }
    *(us8*)dst = o0;
    *(us8*)(dst + 8) = o1;
  }
  __syncthreads();
  {
    const int dr = tid >> 2, qp = (tid & 3) * 16;
    us8 a, c;
#pragma unroll
    for (int i = 0; i < 8; ++i) a[i] = t[qp + i][dr];
#pragma unroll
    for (int i = 0; i < 8; ++i) c[i] = t[qp + 8 + i][dr];
    unsigned short* dst = QT + ((size_t)b * DD + d0 + dr) * TQ + q0 + qp;
    *(us8*)dst = a;
    *(us8*)(dst + 8) = c;
  }
}

// ---------------------------------------------------------------------------
// Kernel A: per (batch, 64-row c-tile), 512 threads = 8 waves; wave tile
// 64c x 32q (sim) / 64c x 32d (PV) -> acc[4][2] = 32 AGPRs. Target: arch
// VGPR + AGPR <= 128 so 4 waves/SIMD (16 waves/CU) are resident.
// fp16 MFMA; C staged once in LDS; Q from global (L2) with reg prefetch.
// Emits q2c per-tile partials (pnum split in 2 row-halves, ptM, ptD).
// ---------------------------------------------------------------------------
__global__ __launch_bounds__(512, 4)
void kA(const float* __restrict__ Cg, const unsigned short* __restrict__ Qh,
        const unsigned short* __restrict__ QT,
        const int* __restrict__ clenp, const int* __restrict__ qlenp,
        float* __restrict__ out1, float* __restrict__ pnum,
        float* __restrict__ ptM, float* __restrict__ ptD)
{
  __shared__ __align__(16) char lds[32768];  // bufC (fp16), later bufP
  __shared__ float red[512];                 // [8 waves][64 rows]
  __shared__ float wred[64];                 // row max M_c
  __shared__ float wexp[64];                 // exp(M_c - mtile)
  __shared__ float sinv[64];                 // 1 / row softmax sum
  char* const bufC = lds;
  char* const bufP = lds;

  const int bid = blockIdx.x;
  const int b = bid & 31;                   // batch -> fixed XCD (bid%8 == b%8)
  const int tile = bid >> 5;                // 0..31
  const int c0 = tile * CR;
  const int tid = threadIdx.x;
  const int l = tid & 63, wid = tid >> 6;   // 8 waves
  const int g = l >> 4, lm = l & 15;
  const int clen = clenp[b], qlen = qlenp[b];

  const float* Cb = Cg + (size_t)(b * TC + c0) * DD;
  const unsigned short* Qhb = Qh + (size_t)b * TQ * DD;
  const unsigned short* QTb = QT + (size_t)b * DD * TQ;

  // ---- stage C tile once: 64 rows x 256 d fp32 -> fp16 LDS ----
  {
    const int r = tid >> 3;                 // 64 rows, 8 threads/row
    const int d0 = (tid & 7) * 32;
    const float* src = Cb + (size_t)r * DD + d0;
#pragma unroll
    for (int i = 0; i < 4; ++i) {
      us8 h;
#pragma unroll
      for (int k = 0; k < 8; k += 4) {
        float4v v = *(const float4v*)(src + i * 8 + k);
#pragma unroll
        for (int j = 0; j < 4; ++j) h[k + j] = f2h(v[j]);
      }
      *(us8*)(bufC + r * 512 + swz(r, (d0 + i * 8) * 2)) = h;
    }
  }
  __syncthreads();   // bar1

  f32x4 acc[4][2];
#pragma unroll
  for (int mt = 0; mt < 4; ++mt)
#pragma unroll
    for (int nt = 0; nt < 2; ++nt) acc[mt][nt] = (f32x4)0.0f;

  // ---- sim: A (C rows) from LDS, B (Q rows) from global, prefetched ----
  us8 bh[2][2];
#pragma unroll
  for (int nt = 0; nt < 2; ++nt)
    bh[0][nt] = *(const us8*)(Qhb + (size_t)(wid * 32 + nt * 16 + lm) * DD + g * 8);
#pragma unroll
  for (int kk = 0; kk < 8; ++kk) {
    const int cur = kk & 1, nxt = cur ^ 1;
    if (kk < 7) {
#pragma unroll
      for (int nt = 0; nt < 2; ++nt)
        bh[nxt][nt] = *(const us8*)(Qhb + (size_t)(wid * 32 + nt * 16 + lm) * DD +
                                    (kk + 1) * 32 + g * 8);
    }
    us8 ah[4];
#pragma unroll
    for (int mt = 0; mt < 4; ++mt) {
      const int row = mt * 16 + lm;
      ah[mt] = *(const us8*)(bufC + row * 512 + swz(row, kk * 64 + g * 16));
    }
#pragma unroll
    for (int mt = 0; mt < 4; ++mt)
#pragma unroll
      for (int nt = 0; nt < 2; ++nt)
        acc[mt][nt] = mfmah(ah[mt], bh[cur][nt], acc[mt][nt]);
  }

  // ---- mask (exact fp32 absorption to -1e29, as reference) ----
#pragma unroll
  for (int nt = 0; nt < 2; ++nt) {
    const int q = wid * 32 + nt * 16 + lm;
    const bool qm = q >= qlen;
#pragma unroll
    for (int mt = 0; mt < 4; ++mt)
#pragma unroll
      for (int j = 0; j < 4; ++j) {
        const int c = c0 + mt * 16 + g * 4 + j;
        if (qm || c >= clen) acc[mt][nt][j] = VNEG;
      }
  }

  // ---- softmax over q (wave-local shuffle + cross-wave LDS, 8 waves) ----
  float rmax[4][4];
#pragma unroll
  for (int mt = 0; mt < 4; ++mt)
#pragma unroll
    for (int j = 0; j < 4; ++j) {
      float m = fmaxf(acc[mt][0][j], acc[mt][1][j]);
      m = fmaxf(m, __shfl_xor(m, 1, 64));
      m = fmaxf(m, __shfl_xor(m, 2, 64));
      m = fmaxf(m, __shfl_xor(m, 4, 64));
      m = fmaxf(m, __shfl_xor(m, 8, 64));
      rmax[mt][j] = m;
    }
  if (lm == 0) {
#pragma unroll
    for (int mt = 0; mt < 4; ++mt)
#pragma unroll
      for (int j = 0; j < 4; ++j)
        red[wid * 64 + mt * 16 + g * 4 + j] = rmax[mt][j];
  }
  __syncthreads();   // bar2
#pragma unroll
  for (int mt = 0; mt < 4; ++mt)
#pragma unroll
    for (int j = 0; j < 4; ++j) {
      const int row = mt * 16 + g * 4 + j;
      const float m0 = fmaxf(fmaxf(red[row], red[64 + row]),
                             fmaxf(red[128 + row], red[192 + row]));
      const float m1 = fmaxf(fmaxf(red[256 + row], red[320 + row]),
                             fmaxf(red[384 + row], red[448 + row]));
      rmax[mt][j] = fmaxf(m0, m1);
      if (wid == 0 && lm == 0) wred[row] = rmax[mt][j];
    }
  // tile max (over all 64 rows): local then across lane groups
  float mtile;
  {
    float m = rmax[0][0];
#pragma unroll
    for (int mt = 0; mt < 4; ++mt)
#pragma unroll
      for (int j = 0; j < 4; ++j) m = fmaxf(m, rmax[mt][j]);
    m = fmaxf(m, __shfl_xor(m, 16, 64));
    m = fmaxf(m, __shfl_xor(m, 32, 64));
    mtile = m;
  }
  // exp + wave partial sums -> red
#pragma unroll
  for (int mt = 0; mt < 4; ++mt)
#pragma unroll
    for (int j = 0; j < 4; ++j) {
      float s = 0.f;
#pragma unroll
      for (int nt = 0; nt < 2; ++nt) {
        const float p = __expf(acc[mt][nt][j] - rmax[mt][j]);
        acc[mt][nt][j] = p;
        s += p;
      }
      s += __shfl_xor(s, 1, 64);
      s += __shfl_xor(s, 2, 64);
      s += __shfl_xor(s, 4, 64);
      s += __shfl_xor(s, 8, 64);
      if (lm == 0) red[wid * 64 + mt * 16 + g * 4 + j] = s;
    }
  __syncthreads();   // bar3 (red-max reads done; red sums + wred visible)
  if (wid == 0) {
    const float wv = __expf(wred[l] - mtile);
    wexp[l] = wv;
    float s = wv;
    s += __shfl_xor(s, 1, 64);  s += __shfl_xor(s, 2, 64);
    s += __shfl_xor(s, 4, 64);  s += __shfl_xor(s, 8, 64);
    s += __shfl_xor(s, 16, 64); s += __shfl_xor(s, 32, 64);
    if (l == 0) { ptD[b * 32 + tile] = s; ptM[b * 32 + tile] = mtile; }
  }
  if (tid < 64) {    // per-row softmax denominator -> 1/sum in LDS
    float s = 0.f;
#pragma unroll
    for (int w = 0; w < 8; ++w) s += red[w * 64 + tid];
    sinv[tid] = 1.0f / s;
  }
  __syncthreads();   // bar4 (wexp + sinv visible)

  // ---- q2c partial from LDS C-tile: pnum[half][d] = sum_{r in half} wexp[r]*C[r,d]
  {
    const int half = tid >> 8;              // 0/1 -> rows 0..31 / 32..63
    const int d = tid & 255;
    float qacc = 0.f;
    const int d2 = d * 2;
#pragma unroll 8
    for (int r = half * 32; r < half * 32 + 32; ++r) {
      const float cv = h2f(*(const unsigned short*)(bufC + r * 512 + swz(r, d2)));
      qacc += wexp[r] * cv;
    }
    pnum[(((size_t)b * 32 + tile) * 2 + half) * DD + d] = qacc;
  }
  __syncthreads();   // bar5 (bufC reads done; safe to overwrite with P)

  // ---- write P (un-normalized exp, fp16) into bufP (aliases bufC) ----
#pragma unroll
  for (int mt = 0; mt < 4; ++mt)
#pragma unroll
    for (int nt = 0; nt < 2; ++nt)
#pragma unroll
      for (int j = 0; j < 4; ++j) {
        const int row = mt * 16 + g * 4 + j;
        const int cb = (wid * 32 + nt * 16 + lm) * 2;
        *(unsigned short*)(bufP + row * 512 + swz(row, cb)) = f2h(acc[mt][nt][j]);
      }
  __syncthreads();   // bar6 (P visible; sinv safely ordered before epilogue)

  // ---- PV: out1 = P @ Q; A from LDS P, B from global QT, prefetched ----
  f32x4 pacc[4][2];
#pragma unroll
  for (int mt = 0; mt < 4; ++mt)
#pragma unroll
    for (int dt = 0; dt < 2; ++dt) pacc[mt][dt] = (f32x4)0.0f;

  us8 qb[2][2];
#pragma unroll
  for (int dt = 0; dt < 2; ++dt)
    qb[0][dt] = *(const us8*)(QTb + (size_t)(wid * 32 + dt * 16 + lm) * TQ + g * 8);
#pragma unroll
  for (int kq = 0; kq < 8; ++kq) {
    const int cur = kq & 1, nxt = cur ^ 1;
    if (kq < 7) {
#pragma unroll
      for (int dt = 0; dt < 2; ++dt)
        qb[nxt][dt] = *(const us8*)(QTb + (size_t)(wid * 32 + dt * 16 + lm) * TQ +
                                    (kq + 1) * 32 + g * 8);
    }
    us8 pa[4];
#pragma unroll
    for (int mt = 0; mt < 4; ++mt) {
      const int row = mt * 16 + lm;
      pa[mt] = *(const us8*)(bufP + row * 512 + swz(row, kq * 64 + g * 16));
    }
#pragma unroll
    for (int mt = 0; mt < 4; ++mt)
#pragma unroll
      for (int dt = 0; dt < 2; ++dt)
        pacc[mt][dt] = mfmah(pa[mt], qb[cur][dt], pacc[mt][dt]);
  }

  // ---- epilogue: normalize (1/sum from LDS) and store ----
#pragma unroll
  for (int mt = 0; mt < 4; ++mt)
#pragma unroll
    for (int j = 0; j < 4; ++j) {
      const int row = mt * 16 + g * 4 + j;
      const float inv = sinv[row];
      const size_t rowoff = (size_t)(b * TC + c0 + row) * DD;
#pragma unroll
      for (int dt = 0; dt < 2; ++dt)
        out1[rowoff + wid * 32 + dt * 16 + lm] = pacc[mt][dt][j] * inv;
    }
}

// ---------------------------------------------------------------------------
// kComb: q2c[b,d] = sum_t e^{ptM_t - m} (pnum[t,0,d]+pnum[t,1,d]) /
//                   (sum_t e^{ptM_t - m} ptD_t)
// ---------------------------------------------------------------------------
__global__ void kComb(const float* __restrict__ pnum, const float* __restrict__ ptM,
                      const float* __restrict__ ptD, float* __restrict__ q2c)
{
  const int b = blockIdx.x, tid = threadIdx.x;
  __shared__ float sM[32], sD[32];
  if (tid < 32) { sM[tid] = ptM[b * 32 + tid]; sD[tid] = ptD[b * 32 + tid]; }
  __syncthreads();
  float m = sM[0];
#pragma unroll
  for (int t = 1; t < 32; ++t) m = fmaxf(m, sM[t]);
  float den = 0.f, acc = 0.f;
#pragma unroll
  for (int t = 0; t < 32; ++t) {
    const float sc = __expf(sM[t] - m);
    den += sc * sD[t];
    const size_t base = (((size_t)b * 32 + t) * 2) * DD + tid;
    acc += sc * (pnum[base] + pnum[base + DD]);
  }
  q2c[b * DD + tid] = acc / den;
}

// ---------------------------------------------------------------------------
// kC: broadcast q2c[b,d] -> out2[b, c-seg, d]
// ---------------------------------------------------------------------------
__global__ void kC(const float* __restrict__ q2c, float* __restrict__ out2)
{
  const int b = blockIdx.x >> 4, seg = blockIdx.x & 15;
  const int d = threadIdx.x;
  const float s = q2c[b * DD + d];
  float* dst = out2 + ((size_t)b * TC + seg * 128) * DD + d;
#pragma unroll 4
  for (int c = 0; c < 128; ++c) dst[(size_t)c * DD] = s;
}

extern "C" void kernel_launch(void* const* d_in, const int* in_sizes, int n_in,
                              void* d_out, int out_size, void* d_ws, size_t ws_size,
                              hipStream_t stream)
{
  const float* Cg = (const float*)d_in[0];
  const float* Qg = (const float*)d_in[1];
  const int* clen = (const int*)d_in[2];
  const int* qlen = (const int*)d_in[3];
  float* out1 = (float*)d_out;
  float* out2 = out1 + (size_t)NB * TC * DD;

  char* ws = (char*)d_ws;
  float* pnum = (float*)(ws);                          // 32*32*2*256 f32 = 2 MB
  float* ptM  = (float*)(ws + 2097152);                // 1024 f32
  float* ptD  = (float*)(ws + 2101248);                // 1024 f32
  float* q2c  = (float*)(ws + 2105344);                // 32*256 f32
  unsigned short* Qh = (unsigned short*)(ws + 2138112);          // 4 MB
  unsigned short* QT = (unsigned short*)(ws + 2138112 + 4194304);// 4 MB

  P0   <<<dim3(512), dim3(256), 0, stream>>>(Qg, Qh, QT);
  kA   <<<dim3(NB * (TC / CR)), dim3(512), 0, stream>>>(Cg, Qh, QT, clen, qlen,
                                                        out1, pnum, ptM, ptD);
  kComb<<<dim3(NB), dim3(256), 0, stream>>>(pnum, ptM, ptD, q2c);
  kC   <<<dim3(NB * 16), dim3(256), 0, stream>>>(q2c, out2);
}

// Round 8
// 83.034 us; speedup vs baseline: 1.2973x; 1.0378x over previous
//
#include <hip/hip_runtime.h>
#include <hip/hip_fp16.h>

#define DEVI __device__ __forceinline__

typedef float f32x4 __attribute__((ext_vector_type(4)));
typedef float float4v __attribute__((ext_vector_type(4)));
typedef _Float16 f16x8 __attribute__((ext_vector_type(8)));
typedef unsigned short us8 __attribute__((ext_vector_type(8)));

constexpr int NB = 32, TC = 2048, TQ = 256, DD = 256;
constexpr int CR = 64;                      // c-rows per kA block
constexpr float VNEG = -1e29f;

DEVI unsigned short f2h(float f) {
  _Float16 h = (_Float16)f;                 // v_cvt_f16_f32 (RN)
  return __builtin_bit_cast(unsigned short, h);
}
DEVI float h2f(unsigned short u) {
  return (float)__builtin_bit_cast(_Float16, u);
}

// XOR swizzle on 16B granules within a 512B row; involution (write==read).
DEVI int swz(int row, int cb) { return cb ^ (((row ^ (cb >> 7)) & 7) << 4); }

DEVI f32x4 mfmah(us8 a, us8 b, f32x4 c) {
  return __builtin_amdgcn_mfma_f32_16x16x32_f16(
      __builtin_bit_cast(f16x8, a), __builtin_bit_cast(f16x8, b), c, 0, 0, 0);
}

// ---------------------------------------------------------------------------
// P0: one pass over Q producing Qh (fp16 row-major) AND QT (fp16 transposed).
// 512 blocks: one 64x64 tile each.
// ---------------------------------------------------------------------------
__global__ void P0(const float* __restrict__ Qg, unsigned short* __restrict__ Qh,
                   unsigned short* __restrict__ QT)
{
  __shared__ unsigned short t[64][72];
  const int bid = blockIdx.x, tid = threadIdx.x;
  const int b = bid >> 4;
  const int q0 = ((bid >> 2) & 3) * 64, d0 = (bid & 3) * 64;
  {
    const int qr = tid >> 2, dp = (tid & 3) * 16;
    const float* src = Qg + ((size_t)b * TQ + q0 + qr) * DD + d0 + dp;
    unsigned short* dst = Qh + ((size_t)b * TQ + q0 + qr) * DD + d0 + dp;
    us8 o0, o1;
#pragma unroll
    for (int i = 0; i < 4; ++i) {
      float4v v = *(const float4v*)(src + i * 4);
#pragma unroll
      for (int j = 0; j < 4; ++j) {
        const unsigned short h = f2h(v[j]);
        t[qr][dp + i * 4 + j] = h;
        if (i < 2) o0[i * 4 + j] = h; else o1[(i - 2) * 4 + j] = h;
      }
    }
    *(us8*)dst = o0;
    *(us8*)(dst + 8) = o1;
  }
  __syncthreads();
  {
    const int dr = tid >> 2, qp = (tid & 3) * 16;
    us8 a, c;
#pragma unroll
    for (int i = 0; i < 8; ++i) a[i] = t[qp + i][dr];
#pragma unroll
    for (int i = 0; i < 8; ++i) c[i] = t[qp + 8 + i][dr];
    unsigned short* dst = QT + ((size_t)b * DD + d0 + dr) * TQ + q0 + qp;
    *(us8*)dst = a;
    *(us8*)(dst + 8) = c;
  }
}

// ---------------------------------------------------------------------------
// Kernel A: per (batch, 64-row c-tile), 512 threads = 8 waves; wave tile
// 64c x 32q (sim) / 64c x 32d (PV) -> acc 32 AGPRs. Row maxima kept in LDS
// (wred), not registers, so arch+AGPR fits the 6-waves/SIMD budget (~85).
// fp16 MFMA; C staged once in LDS; Q from global (L2) with reg prefetch.
// Emits q2c per-tile partials (pnum split in 2 row-halves, ptM, ptD).
// ---------------------------------------------------------------------------
__global__ __launch_bounds__(512, 6)
void kA(const float* __restrict__ Cg, const unsigned short* __restrict__ Qh,
        const unsigned short* __restrict__ QT,
        const int* __restrict__ clenp, const int* __restrict__ qlenp,
        float* __restrict__ out1, float* __restrict__ pnum,
        float* __restrict__ ptM, float* __restrict__ ptD)
{
  __shared__ __align__(16) char lds[32768];  // bufC (fp16), later bufP
  __shared__ float redM[512];                // per-wave row maxima
  __shared__ float redS[512];                // per-wave row sums
  __shared__ float wred[64];                 // global row max M_c
  __shared__ float wexp[64];                 // exp(M_c - mtile)
  __shared__ float sinv[64];                 // 1 / row softmax sum
  char* const bufC = lds;
  char* const bufP = lds;

  const int bid = blockIdx.x;
  const int b = bid & 31;                   // batch -> fixed XCD (bid%8 == b%8)
  const int tile = bid >> 5;                // 0..31
  const int c0 = tile * CR;
  const int tid = threadIdx.x;
  const int l = tid & 63, wid = tid >> 6;   // 8 waves
  const int g = l >> 4, lm = l & 15;
  const int clen = clenp[b], qlen = qlenp[b];

  const float* Cb = Cg + (size_t)(b * TC + c0) * DD;
  const unsigned short* Qhb = Qh + (size_t)b * TQ * DD;
  const unsigned short* QTb = QT + (size_t)b * DD * TQ;

  // ---- stage C tile once: 64 rows x 256 d fp32 -> fp16 LDS ----
  {
    const int r = tid >> 3;                 // 64 rows, 8 threads/row
    const int d0 = (tid & 7) * 32;
    const float* src = Cb + (size_t)r * DD + d0;
#pragma unroll
    for (int i = 0; i < 4; ++i) {
      us8 h;
#pragma unroll
      for (int k = 0; k < 8; k += 4) {
        float4v v = *(const float4v*)(src + i * 8 + k);
#pragma unroll
        for (int j = 0; j < 4; ++j) h[k + j] = f2h(v[j]);
      }
      *(us8*)(bufC + r * 512 + swz(r, (d0 + i * 8) * 2)) = h;
    }
  }
  __syncthreads();   // bar1

  f32x4 acc[4][2];
#pragma unroll
  for (int mt = 0; mt < 4; ++mt)
#pragma unroll
    for (int nt = 0; nt < 2; ++nt) acc[mt][nt] = (f32x4)0.0f;

  // ---- sim: A (C rows) from LDS, B (Q rows) from global, prefetched ----
  us8 bh[2][2];
#pragma unroll
  for (int nt = 0; nt < 2; ++nt)
    bh[0][nt] = *(const us8*)(Qhb + (size_t)(wid * 32 + nt * 16 + lm) * DD + g * 8);
#pragma unroll
  for (int kk = 0; kk < 8; ++kk) {
    const int cur = kk & 1, nxt = cur ^ 1;
    if (kk < 7) {
#pragma unroll
      for (int nt = 0; nt < 2; ++nt)
        bh[nxt][nt] = *(const us8*)(Qhb + (size_t)(wid * 32 + nt * 16 + lm) * DD +
                                    (kk + 1) * 32 + g * 8);
    }
    us8 ah[4];
#pragma unroll
    for (int mt = 0; mt < 4; ++mt) {
      const int row = mt * 16 + lm;
      ah[mt] = *(const us8*)(bufC + row * 512 + swz(row, kk * 64 + g * 16));
    }
#pragma unroll
    for (int mt = 0; mt < 4; ++mt)
#pragma unroll
      for (int nt = 0; nt < 2; ++nt)
        acc[mt][nt] = mfmah(ah[mt], bh[cur][nt], acc[mt][nt]);
  }

  // ---- mask (exact fp32 absorption to -1e29, as reference) ----
#pragma unroll
  for (int nt = 0; nt < 2; ++nt) {
    const int q = wid * 32 + nt * 16 + lm;
    const bool qm = q >= qlen;
#pragma unroll
    for (int mt = 0; mt < 4; ++mt)
#pragma unroll
      for (int j = 0; j < 4; ++j) {
        const int c = c0 + mt * 16 + g * 4 + j;
        if (qm || c >= clen) acc[mt][nt][j] = VNEG;
      }
  }

  // ---- per-wave row maxima -> redM ----
#pragma unroll
  for (int mt = 0; mt < 4; ++mt)
#pragma unroll
    for (int j = 0; j < 4; ++j) {
      float m = fmaxf(acc[mt][0][j], acc[mt][1][j]);
      m = fmaxf(m, __shfl_xor(m, 1, 64));
      m = fmaxf(m, __shfl_xor(m, 2, 64));
      m = fmaxf(m, __shfl_xor(m, 4, 64));
      m = fmaxf(m, __shfl_xor(m, 8, 64));
      if (lm == 0) redM[wid * 64 + mt * 16 + g * 4 + j] = m;
    }
  __syncthreads();   // bar2 (redM complete)

  // ---- global row maxima -> wred (first 64 threads) ----
  if (tid < 64) {
    float m = redM[tid];
#pragma unroll
    for (int w = 1; w < 8; ++w) m = fmaxf(m, redM[w * 64 + tid]);
    wred[tid] = m;
  }
  __syncthreads();   // bar3 (wred visible)

  // ---- exp + per-wave row sums -> redS (row max read from LDS) ----
#pragma unroll
  for (int mt = 0; mt < 4; ++mt)
#pragma unroll
    for (int j = 0; j < 4; ++j) {
      const float m = wred[mt * 16 + g * 4 + j];
      float s = 0.f;
#pragma unroll
      for (int nt = 0; nt < 2; ++nt) {
        const float p = __expf(acc[mt][nt][j] - m);
        acc[mt][nt][j] = p;
        s += p;
      }
      s += __shfl_xor(s, 1, 64);
      s += __shfl_xor(s, 2, 64);
      s += __shfl_xor(s, 4, 64);
      s += __shfl_xor(s, 8, 64);
      if (lm == 0) redS[wid * 64 + mt * 16 + g * 4 + j] = s;
    }
  // ---- tile max + wexp + ptM/ptD (wave 0; wred is stable after bar3) ----
  if (wid == 0) {
    float m = wred[l];
    m = fmaxf(m, __shfl_xor(m, 1, 64));  m = fmaxf(m, __shfl_xor(m, 2, 64));
    m = fmaxf(m, __shfl_xor(m, 4, 64));  m = fmaxf(m, __shfl_xor(m, 8, 64));
    m = fmaxf(m, __shfl_xor(m, 16, 64)); m = fmaxf(m, __shfl_xor(m, 32, 64));
    const float wv = __expf(wred[l] - m);
    wexp[l] = wv;
    float s = wv;
    s += __shfl_xor(s, 1, 64);  s += __shfl_xor(s, 2, 64);
    s += __shfl_xor(s, 4, 64);  s += __shfl_xor(s, 8, 64);
    s += __shfl_xor(s, 16, 64); s += __shfl_xor(s, 32, 64);
    if (l == 0) { ptD[b * 32 + tile] = s; ptM[b * 32 + tile] = m; }
  }
  __syncthreads();   // bar4 (redS + wexp visible)

  // ---- per-row 1/sum -> sinv ----
  if (tid < 64) {
    float s = 0.f;
#pragma unroll
    for (int w = 0; w < 8; ++w) s += redS[w * 64 + tid];
    sinv[tid] = 1.0f / s;
  }

  // ---- q2c partial from LDS C-tile: pnum[half][d] = sum_{r in half} wexp[r]*C[r,d]
  {
    const int half = tid >> 8;              // 0/1 -> rows 0..31 / 32..63
    const int d = tid & 255;
    float qacc = 0.f;
    const int d2 = d * 2;
#pragma unroll 8
    for (int r = half * 32; r < half * 32 + 32; ++r) {
      const float cv = h2f(*(const unsigned short*)(bufC + r * 512 + swz(r, d2)));
      qacc += wexp[r] * cv;
    }
    pnum[(((size_t)b * 32 + tile) * 2 + half) * DD + d] = qacc;
  }
  __syncthreads();   // bar5 (bufC reads done; safe to overwrite with P)

  // ---- write P (un-normalized exp, fp16) into bufP (aliases bufC) ----
#pragma unroll
  for (int mt = 0; mt < 4; ++mt)
#pragma unroll
    for (int nt = 0; nt < 2; ++nt)
#pragma unroll
      for (int j = 0; j < 4; ++j) {
        const int row = mt * 16 + g * 4 + j;
        const int cb = (wid * 32 + nt * 16 + lm) * 2;
        *(unsigned short*)(bufP + row * 512 + swz(row, cb)) = f2h(acc[mt][nt][j]);
      }
  __syncthreads();   // bar6 (P + sinv visible)

  // ---- PV: out1 = P @ Q; A from LDS P, B from global QT, prefetched ----
  f32x4 pacc[4][2];
#pragma unroll
  for (int mt = 0; mt < 4; ++mt)
#pragma unroll
    for (int dt = 0; dt < 2; ++dt) pacc[mt][dt] = (f32x4)0.0f;

  us8 qb[2][2];
#pragma unroll
  for (int dt = 0; dt < 2; ++dt)
    qb[0][dt] = *(const us8*)(QTb + (size_t)(wid * 32 + dt * 16 + lm) * TQ + g * 8);
#pragma unroll
  for (int kq = 0; kq < 8; ++kq) {
    const int cur = kq & 1, nxt = cur ^ 1;
    if (kq < 7) {
#pragma unroll
      for (int dt = 0; dt < 2; ++dt)
        qb[nxt][dt] = *(const us8*)(QTb + (size_t)(wid * 32 + dt * 16 + lm) * TQ +
                                    (kq + 1) * 32 + g * 8);
    }
    us8 pa[4];
#pragma unroll
    for (int mt = 0; mt < 4; ++mt) {
      const int row = mt * 16 + lm;
      pa[mt] = *(const us8*)(bufP + row * 512 + swz(row, kq * 64 + g * 16));
    }
#pragma unroll
    for (int mt = 0; mt < 4; ++mt)
#pragma unroll
      for (int dt = 0; dt < 2; ++dt)
        pacc[mt][dt] = mfmah(pa[mt], qb[cur][dt], pacc[mt][dt]);
  }

  // ---- epilogue: normalize (1/sum from LDS) and store ----
#pragma unroll
  for (int mt = 0; mt < 4; ++mt)
#pragma unroll
    for (int j = 0; j < 4; ++j) {
      const int row = mt * 16 + g * 4 + j;
      const float inv = sinv[row];
      const size_t rowoff = (size_t)(b * TC + c0 + row) * DD;
#pragma unroll
      for (int dt = 0; dt < 2; ++dt)
        out1[rowoff + wid * 32 + dt * 16 + lm] = pacc[mt][dt][j] * inv;
    }
}

// ---------------------------------------------------------------------------
// kC (fused combine + broadcast): each block recomputes
//   q2c[b,d] = sum_t e^{ptM_t-m}(pnum[t,0,d]+pnum[t,1,d]) / sum_t e^{ptM_t-m} ptD_t
// then broadcasts into its 128-row segment of out2.
// ---------------------------------------------------------------------------
__global__ void kC(const float* __restrict__ pnum, const float* __restrict__ ptM,
                   const float* __restrict__ ptD, float* __restrict__ out2)
{
  const int b = blockIdx.x >> 4, seg = blockIdx.x & 15;
  const int d = threadIdx.x;
  __shared__ float sM[32], sD[32];
  if (d < 32) { sM[d] = ptM[b * 32 + d]; sD[d] = ptD[b * 32 + d]; }
  __syncthreads();
  float m = sM[0];
#pragma unroll
  for (int t = 1; t < 32; ++t) m = fmaxf(m, sM[t]);
  float den = 0.f, acc = 0.f;
#pragma unroll
  for (int t = 0; t < 32; ++t) {
    const float sc = __expf(sM[t] - m);
    den += sc * sD[t];
    const size_t base = (((size_t)b * 32 + t) * 2) * DD + d;
    acc += sc * (pnum[base] + pnum[base + DD]);
  }
  const float s = acc / den;
  float* dst = out2 + ((size_t)b * TC + seg * 128) * DD + d;
#pragma unroll 4
  for (int c = 0; c < 128; ++c) dst[(size_t)c * DD] = s;
}

extern "C" void kernel_launch(void* const* d_in, const int* in_sizes, int n_in,
                              void* d_out, int out_size, void* d_ws, size_t ws_size,
                              hipStream_t stream)
{
  const float* Cg = (const float*)d_in[0];
  const float* Qg = (const float*)d_in[1];
  const int* clen = (const int*)d_in[2];
  const int* qlen = (const int*)d_in[3];
  float* out1 = (float*)d_out;
  float* out2 = out1 + (size_t)NB * TC * DD;

  char* ws = (char*)d_ws;
  float* pnum = (float*)(ws);                          // 32*32*2*256 f32 = 2 MB
  float* ptM  = (float*)(ws + 2097152);                // 1024 f32
  float* ptD  = (float*)(ws + 2101248);                // 1024 f32
  unsigned short* Qh = (unsigned short*)(ws + 2105344);          // 4 MB
  unsigned short* QT = (unsigned short*)(ws + 2105344 + 4194304);// 4 MB

  P0 <<<dim3(512), dim3(256), 0, stream>>>(Qg, Qh, QT);
  kA <<<dim3(NB * (TC / CR)), dim3(512), 0, stream>>>(Cg, Qh, QT, clen, qlen,
                                                      out1, pnum, ptM, ptD);
  kC <<<dim3(NB * 16), dim3(256), 0, stream>>>(pnum, ptM, ptD, out2);
}